// Round 1
// baseline (9994.894 us; speedup 1.0000x reference)
//
#include <hip/hip_runtime.h>
#include <hip/hip_bf16.h>
#include <math.h>

// Problem constants (match reference)
#define SS 2048      // sequence length
#define DD 1024      // model dim
#define NH 16        // q heads
#define NKVH 4       // kv heads
#define HDIM 64      // head dim
#define NE 8         // experts
#define NI 3584      // ffn intermediate
#define QKVN 1536    // (16+2*4)*64
#define RSLOTS (SS*2) // routed token-slots (top-2)

// ---------------- RMSNorm: one block per row ----------------
__global__ void rmsnorm_kernel(const float* __restrict__ x, const float* __restrict__ w,
                               float* __restrict__ out) {
  int row = blockIdx.x;
  const float* xr = x + (size_t)row * DD;
  float ss = 0.f;
  for (int i = threadIdx.x; i < DD; i += 256) { float v = xr[i]; ss += v * v; }
  for (int o = 32; o > 0; o >>= 1) ss += __shfl_xor(ss, o);
  __shared__ float red[4];
  int wid = threadIdx.x >> 6;
  if ((threadIdx.x & 63) == 0) red[wid] = ss;
  __syncthreads();
  float tot = red[0] + red[1] + red[2] + red[3];
  float r = rsqrtf(tot * (1.f / DD) + 1e-5f);
  for (int i = threadIdx.x; i < DD; i += 256)
    out[(size_t)row * DD + i] = xr[i] * r * w[i];
}

// ---------------- Generic tiled GEMM: C[m,n] = sum_k A[m,k]*B[n,k] (+addend) ----------------
// A: [M,K] row-major, B: [N,K] row-major. M,N multiples of 64, K multiple of 16.
__global__ __launch_bounds__(256) void gemm_bt(const float* __restrict__ A,
                                               const float* __restrict__ B,
                                               float* __restrict__ C,
                                               const float* __restrict__ addend,
                                               int M, int N, int K) {
  __shared__ float As[16][65];
  __shared__ float Bs[16][65];
  int bm = blockIdx.x * 64;
  int bn = blockIdx.y * 64;
  int tid = threadIdx.x;
  int tx = tid & 15, ty = tid >> 4;
  float acc[4][4] = {};
  for (int k0 = 0; k0 < K; k0 += 16) {
#pragma unroll
    for (int i = 0; i < 4; i++) {
      int idx = tid + i * 256;
      int kk = idx & 15, mm = idx >> 4;
      As[kk][mm] = A[(size_t)(bm + mm) * K + k0 + kk];
      Bs[kk][mm] = B[(size_t)(bn + mm) * K + k0 + kk];
    }
    __syncthreads();
#pragma unroll
    for (int kk = 0; kk < 16; kk++) {
      float a[4], b[4];
#pragma unroll
      for (int i = 0; i < 4; i++) a[i] = As[kk][ty * 4 + i];
#pragma unroll
      for (int j = 0; j < 4; j++) b[j] = Bs[kk][tx * 4 + j];
#pragma unroll
      for (int i = 0; i < 4; i++)
#pragma unroll
        for (int j = 0; j < 4; j++) acc[i][j] += a[i] * b[j];
    }
    __syncthreads();
  }
#pragma unroll
  for (int i = 0; i < 4; i++) {
    int m = bm + ty * 4 + i;
#pragma unroll
    for (int j = 0; j < 4; j++) {
      int n = bn + tx * 4 + j;
      float v = acc[i][j];
      if (addend) v += addend[(size_t)m * N + n];
      C[(size_t)m * N + n] = v;
    }
  }
}

// ---------------- RoPE in-place on q,k portions of qkv ----------------
__global__ void rope_kernel(float* __restrict__ qkv, const float* __restrict__ freqs) {
  int s = blockIdx.x;
  for (int t = threadIdx.x; t < (NH + NKVH) * 32; t += 256) {
    int hh = t >> 5, i = t & 31;
    int col = (hh < NH) ? hh * HDIM : DD + (hh - NH) * HDIM;
    float* p = qkv + (size_t)s * QKVN + col + 2 * i;
    float c = freqs[(s * 32 + i) * 2];
    float sn = freqs[(s * 32 + i) * 2 + 1];
    float x0 = p[0], x1 = p[1];
    p[0] = x0 * c - x1 * sn;
    p[1] = x1 * c + x0 * sn;
  }
}

// ---------------- Attention: one wave per (head, q-row), online softmax ----------------
__global__ __launch_bounds__(64) void attn_kernel(const float* __restrict__ qkv,
                                                  float* __restrict__ y) {
  int qrow = blockIdx.x;
  int h = blockIdx.y;
  int lane = threadIdx.x;
  int kvh = h >> 2;
  float qd = qkv[(size_t)qrow * QKVN + h * HDIM + lane];
  const float* kbase = qkv + DD + kvh * HDIM + lane;
  const float* vbase = qkv + DD + NKVH * HDIM + kvh * HDIM + lane;
  float m = -1e30f, l = 0.f, acc = 0.f;
  for (int j = 0; j <= qrow; j++) {
    float kv = kbase[(size_t)j * QKVN];
    float s = qd * kv;
    for (int o = 32; o > 0; o >>= 1) s += __shfl_xor(s, o);
    s *= 0.125f; // 1/sqrt(64)
    float mn = fmaxf(m, s);
    float alpha = __expf(m - mn);
    float p = __expf(s - mn);
    float vv = vbase[(size_t)j * QKVN];
    l = l * alpha + p;
    acc = acc * alpha + p * vv;
    m = mn;
  }
  y[(size_t)qrow * DD + h * HDIM + lane] = acc / l;
}

// ---------------- Gate: softmax over 8 experts, top-2, renormalize ----------------
__global__ __launch_bounds__(64) void gate_kernel(const float* __restrict__ hf,
                                                  const float* __restrict__ gw,
                                                  int* __restrict__ ei, float* __restrict__ ew,
                                                  int* __restrict__ cnt) {
  int t = blockIdx.x;
  int lane = threadIdx.x;
  const float* xr = hf + (size_t)t * DD;
  float acc[NE] = {};
  for (int c = 0; c < DD / 64; c++) {
    float xv = xr[lane + 64 * c];
#pragma unroll
    for (int e = 0; e < NE; e++) acc[e] += xv * gw[e * DD + lane + 64 * c];
  }
#pragma unroll
  for (int e = 0; e < NE; e++)
    for (int o = 32; o > 0; o >>= 1) acc[e] += __shfl_xor(acc[e], o);
  if (lane == 0) {
    float mx = acc[0];
    for (int e = 1; e < NE; e++) mx = fmaxf(mx, acc[e]);
    float p[NE], sum = 0.f;
    for (int e = 0; e < NE; e++) { p[e] = __expf(acc[e] - mx); sum += p[e]; }
    for (int e = 0; e < NE; e++) p[e] /= sum;
    int i0 = 0;
    for (int e = 1; e < NE; e++) if (p[e] > p[i0]) i0 = e;
    int i1 = (i0 == 0) ? 1 : 0;
    for (int e = 0; e < NE; e++) if (e != i0 && p[e] > p[i1]) i1 = e;
    float w0 = p[i0], w1 = p[i1], s = w0 + w1;
    ei[t * 2] = i0; ei[t * 2 + 1] = i1;
    ew[t * 2] = w0 / s; ew[t * 2 + 1] = w1 / s;
    atomicAdd(&cnt[i0], 1);
    atomicAdd(&cnt[i1], 1);
  }
}

__global__ void zero_cnt_kernel(int* cnt) {
  if (threadIdx.x < NE) cnt[threadIdx.x] = 0;
}

__global__ void prefix_kernel(const int* __restrict__ cnt, int* __restrict__ off,
                              int* __restrict__ fill) {
  if (threadIdx.x == 0) {
    int acc = 0;
    for (int e = 0; e < NE; e++) { off[e] = acc; acc += cnt[e]; }
    off[NE] = acc;
  }
  if (threadIdx.x < NE) fill[threadIdx.x] = 0;
}

__global__ void fill_kernel(const int* __restrict__ ei, const int* __restrict__ off,
                            int* __restrict__ fill, int* __restrict__ routed_token,
                            int* __restrict__ slot_of) {
  int t = blockIdx.x * blockDim.x + threadIdx.x;
  if (t >= SS) return;
  for (int a = 0; a < 2; a++) {
    int e = ei[t * 2 + a];
    int pos = atomicAdd(&fill[e], 1);
    int slot = off[e] + pos;
    routed_token[slot] = t;
    slot_of[t * 2 + a] = slot;
  }
}

// ---------------- MoE stage 1: x13[slot,i] = silu(hf@w1^T) * (hf@w3^T) ----------------
__global__ __launch_bounds__(256) void moe_stage1(const float* __restrict__ hf,
                                                  const float* __restrict__ w1,
                                                  const float* __restrict__ w3,
                                                  const int* __restrict__ eoff,
                                                  const int* __restrict__ routed_token,
                                                  float* __restrict__ x13) {
  int e = blockIdx.z;
  int off = eoff[e], cnt = eoff[e + 1] - off;
  int bm = blockIdx.x * 64;
  if (bm >= cnt) return;
  int bn = blockIdx.y * 64;
  const float* B1 = w1 + (size_t)e * NI * DD;
  const float* B3 = w3 + (size_t)e * NI * DD;
  __shared__ float As[16][65], Bs1[16][65], Bs3[16][65];
  __shared__ int rows[64];
  int tid = threadIdx.x;
  if (tid < 64) {
    int mm = bm + tid;
    rows[tid] = (mm < cnt) ? routed_token[off + mm] : -1;
  }
  __syncthreads();
  int tx = tid & 15, ty = tid >> 4;
  float acc1[4][4] = {}, acc3[4][4] = {};
  for (int k0 = 0; k0 < DD; k0 += 16) {
#pragma unroll
    for (int i = 0; i < 4; i++) {
      int idx = tid + i * 256;
      int kk = idx & 15, mm = idx >> 4;
      int r = rows[mm];
      As[kk][mm] = (r >= 0) ? hf[(size_t)r * DD + k0 + kk] : 0.f;
      Bs1[kk][mm] = B1[(size_t)(bn + mm) * DD + k0 + kk];
      Bs3[kk][mm] = B3[(size_t)(bn + mm) * DD + k0 + kk];
    }
    __syncthreads();
#pragma unroll
    for (int kk = 0; kk < 16; kk++) {
      float a[4], b1[4], b3[4];
#pragma unroll
      for (int i = 0; i < 4; i++) a[i] = As[kk][ty * 4 + i];
#pragma unroll
      for (int j = 0; j < 4; j++) { b1[j] = Bs1[kk][tx * 4 + j]; b3[j] = Bs3[kk][tx * 4 + j]; }
#pragma unroll
      for (int i = 0; i < 4; i++)
#pragma unroll
        for (int j = 0; j < 4; j++) {
          acc1[i][j] += a[i] * b1[j];
          acc3[i][j] += a[i] * b3[j];
        }
    }
    __syncthreads();
  }
#pragma unroll
  for (int i = 0; i < 4; i++) {
    int mm = ty * 4 + i;
    if (bm + mm < cnt) {
#pragma unroll
      for (int j = 0; j < 4; j++) {
        float v1 = acc1[i][j], v3 = acc3[i][j];
        float sil = v1 / (1.f + __expf(-v1));
        x13[(size_t)(off + bm + mm) * NI + bn + tx * 4 + j] = sil * v3;
      }
    }
  }
}

// ---------------- MoE stage 2: oslot[slot,d] = x13[slot,:] @ w2[e]^T ----------------
__global__ __launch_bounds__(256) void moe_stage2(const float* __restrict__ x13,
                                                  const float* __restrict__ w2,
                                                  const int* __restrict__ eoff,
                                                  float* __restrict__ oslot) {
  int e = blockIdx.z;
  int off = eoff[e], cnt = eoff[e + 1] - off;
  int bm = blockIdx.x * 64;
  if (bm >= cnt) return;
  int bn = blockIdx.y * 64;
  const float* B = w2 + (size_t)e * DD * NI;
  const float* A = x13 + (size_t)off * NI;
  __shared__ float As[16][65], Bs[16][65];
  int tid = threadIdx.x;
  int tx = tid & 15, ty = tid >> 4;
  float acc[4][4] = {};
  for (int k0 = 0; k0 < NI; k0 += 16) {
#pragma unroll
    for (int i = 0; i < 4; i++) {
      int idx = tid + i * 256;
      int kk = idx & 15, mm = idx >> 4;
      As[kk][mm] = (bm + mm < cnt) ? A[(size_t)(bm + mm) * NI + k0 + kk] : 0.f;
      Bs[kk][mm] = B[(size_t)(bn + mm) * NI + k0 + kk];
    }
    __syncthreads();
#pragma unroll
    for (int kk = 0; kk < 16; kk++) {
      float a[4], b[4];
#pragma unroll
      for (int i = 0; i < 4; i++) a[i] = As[kk][ty * 4 + i];
#pragma unroll
      for (int j = 0; j < 4; j++) b[j] = Bs[kk][tx * 4 + j];
#pragma unroll
      for (int i = 0; i < 4; i++)
#pragma unroll
        for (int j = 0; j < 4; j++) acc[i][j] += a[i] * b[j];
    }
    __syncthreads();
  }
#pragma unroll
  for (int i = 0; i < 4; i++) {
    int mm = ty * 4 + i;
    if (bm + mm < cnt) {
#pragma unroll
      for (int j = 0; j < 4; j++)
        oslot[(size_t)(off + bm + mm) * DD + bn + tx * 4 + j] = acc[i][j];
    }
  }
}

// ---------------- Final: out = h + w0*oslot[s0] + w1*oslot[s1] ----------------
__global__ void final_kernel(const float* __restrict__ h, const float* __restrict__ oslot,
                             const int* __restrict__ slot_of, const float* __restrict__ ew,
                             float* __restrict__ out) {
  int t = blockIdx.x;
  int s0 = slot_of[t * 2], s1 = slot_of[t * 2 + 1];
  float w0 = ew[t * 2], w1 = ew[t * 2 + 1];
  const float* hr = h + (size_t)t * DD;
  const float* o0 = oslot + (size_t)s0 * DD;
  const float* o1 = oslot + (size_t)s1 * DD;
  float* orow = out + (size_t)t * DD;
  for (int i = threadIdx.x; i < DD; i += 256)
    orow[i] = hr[i] + w0 * o0[i] + w1 * o1[i];
}

extern "C" void kernel_launch(void* const* d_in, const int* in_sizes, int n_in,
                              void* d_out, int out_size, void* d_ws, size_t ws_size,
                              hipStream_t stream) {
  const float* x = (const float*)d_in[0];
  const float* wqkv = (const float*)d_in[1];
  const float* wo = (const float*)d_in[2];
  const float* gate_w = (const float*)d_in[3];
  const float* w1 = (const float*)d_in[4];
  const float* w2 = (const float*)d_in[5];
  const float* w3 = (const float*)d_in[6];
  const float* attn_norm_w = (const float*)d_in[7];
  const float* ffn_norm_w = (const float*)d_in[8];
  const float* freqs = (const float*)d_in[9];
  float* out = (float*)d_out;

  // workspace carve-up
  char* ws = (char*)d_ws;
  size_t off = 0;
  auto alloc = [&](size_t bytes) -> char* {
    char* p = ws + off;
    off = (off + bytes + 255) & ~(size_t)255;
    return p;
  };
  float* hn    = (float*)alloc((size_t)SS * DD * 4);
  float* qkv   = (float*)alloc((size_t)SS * QKVN * 4);
  float* y     = (float*)alloc((size_t)SS * DD * 4);
  float* hbuf  = (float*)alloc((size_t)SS * DD * 4);
  float* hf    = (float*)alloc((size_t)SS * DD * 4);
  float* x13   = (float*)alloc((size_t)RSLOTS * NI * 4);
  float* oslot = (float*)alloc((size_t)RSLOTS * DD * 4);
  int*   ei    = (int*)alloc((size_t)SS * 2 * 4);
  float* ew    = (float*)alloc((size_t)SS * 2 * 4);
  int*   slot_of = (int*)alloc((size_t)SS * 2 * 4);
  int*   routed_token = (int*)alloc((size_t)RSLOTS * 4);
  int*   cnt   = (int*)alloc(NE * 4);
  int*   eoff  = (int*)alloc((NE + 1) * 4);
  int*   fill  = (int*)alloc(NE * 4);

  // ---- attention path ----
  zero_cnt_kernel<<<1, 64, 0, stream>>>(cnt);
  rmsnorm_kernel<<<SS, 256, 0, stream>>>(x, attn_norm_w, hn);
  gemm_bt<<<dim3(SS / 64, QKVN / 64), 256, 0, stream>>>(hn, wqkv, qkv, nullptr, SS, QKVN, DD);
  rope_kernel<<<SS, 256, 0, stream>>>(qkv, freqs);
  attn_kernel<<<dim3(SS, NH), 64, 0, stream>>>(qkv, y);
  gemm_bt<<<dim3(SS / 64, DD / 64), 256, 0, stream>>>(y, wo, hbuf, x, SS, DD, DD);

  // ---- MoE path ----
  rmsnorm_kernel<<<SS, 256, 0, stream>>>(hbuf, ffn_norm_w, hf);
  gate_kernel<<<SS, 64, 0, stream>>>(hf, gate_w, ei, ew, cnt);
  prefix_kernel<<<1, 64, 0, stream>>>(cnt, eoff, fill);
  fill_kernel<<<(SS + 255) / 256, 256, 0, stream>>>(ei, eoff, fill, routed_token, slot_of);
  moe_stage1<<<dim3(RSLOTS / 64, NI / 64, NE), 256, 0, stream>>>(hf, w1, w3, eoff, routed_token, x13);
  moe_stage2<<<dim3(RSLOTS / 64, DD / 64, NE), 256, 0, stream>>>(x13, w2, eoff, oslot);
  final_kernel<<<SS, 256, 0, stream>>>(hbuf, oslot, slot_of, ew, out);
}

// Round 2
// 3674.253 us; speedup vs baseline: 2.7203x; 2.7203x over previous
//
#include <hip/hip_runtime.h>
#include <hip/hip_bf16.h>
#include <math.h>

#define SS 2048
#define DD 1024
#define NH 16
#define NKVH 4
#define HDIM 64
#define NE 8
#define NI 3584
#define QKVN 1536
#define PCAP 5120   // padded slot capacity (4096 real + 8*128 max pad)

typedef unsigned short u16;
typedef short short8 __attribute__((ext_vector_type(8)));
typedef float floatx4 __attribute__((ext_vector_type(4)));

__device__ inline u16 f2bf(float f) {
  unsigned u = __float_as_uint(f);
  unsigned r = u + 0x7fffu + ((u >> 16) & 1u);
  return (u16)(r >> 16);
}
__device__ inline float bf2f(u16 h) { return __uint_as_float((unsigned)h << 16); }

// ---------------- fp32 -> bf16 bulk convert ----------------
__global__ void f32_to_bf16_kernel(const float* __restrict__ in, u16* __restrict__ out, int n4) {
  int i = blockIdx.x * 256 + threadIdx.x;
  if (i >= n4) return;
  float4 v = ((const float4*)in)[i];
  ushort4 o = make_ushort4(f2bf(v.x), f2bf(v.y), f2bf(v.z), f2bf(v.w));
  ((ushort4*)out)[i] = o;
}

// ---------------- RMSNorm: one block per row, optional fp32/bf16 outputs ----------------
__global__ void rmsnorm_kernel(const float* __restrict__ x, const float* __restrict__ w,
                               float* __restrict__ o32, u16* __restrict__ o16) {
  int row = blockIdx.x;
  int t = threadIdx.x;
  float4 v = ((const float4*)(x + (size_t)row * DD))[t];
  float ss = v.x * v.x + v.y * v.y + v.z * v.z + v.w * v.w;
  for (int o = 32; o > 0; o >>= 1) ss += __shfl_xor(ss, o);
  __shared__ float red[4];
  if ((t & 63) == 0) red[t >> 6] = ss;
  __syncthreads();
  float tot = red[0] + red[1] + red[2] + red[3];
  float r = rsqrtf(tot * (1.f / DD) + 1e-5f);
  float4 wv = ((const float4*)w)[t];
  float4 o;
  o.x = v.x * r * wv.x; o.y = v.y * r * wv.y; o.z = v.z * r * wv.z; o.w = v.w * r * wv.w;
  if (o32) ((float4*)(o32 + (size_t)row * DD))[t] = o;
  if (o16) ((ushort4*)(o16 + (size_t)row * DD))[t] =
      make_ushort4(f2bf(o.x), f2bf(o.y), f2bf(o.z), f2bf(o.w));
}

// ---------------- MFMA GEMM: C[m,n] = sum_k A[m,k]*B[n,k] ----------------
// A,B bf16 row-major (A: M x K, B: N x K). 128x128 tile, BK=32, 4 waves.
// If poff != nullptr: MoE mode — blockIdx.z = expert, rows come from padded slot
// range [poff[e], poff[e+1]) (multiple of 128), B += e*bstride.
template <bool OUTBF16>
__global__ __launch_bounds__(256) void gemm128(
    const u16* __restrict__ A, const u16* __restrict__ B,
    void* __restrict__ Cv, const float* __restrict__ addend,
    int N, int K, const int* __restrict__ poff, long long bstride) {
  __shared__ u16 As[128 * 32];
  __shared__ u16 Bs[128 * 32];
  int tid = threadIdx.x;
  int bm = blockIdx.x * 128;
  int bn = blockIdx.y * 128;
  size_t crow0 = 0;
  if (poff) {
    int e = blockIdx.z;
    int off = poff[e];
    int pcnt = poff[e + 1] - off;
    if (bm >= pcnt) return;
    A += (size_t)off * K;
    crow0 = (size_t)off;
    B += (size_t)e * bstride;
  }
  const u16* Ag = A + (size_t)bm * K;
  const u16* Bg = B + (size_t)bn * K;
  int wave = tid >> 6, lane = tid & 63;
  int wm = wave >> 1, wn = wave & 1;
  int ml = lane & 15, quad = lane >> 4;

  floatx4 zero = {0.f, 0.f, 0.f, 0.f};
  floatx4 acc[4][4];
#pragma unroll
  for (int i = 0; i < 4; i++)
#pragma unroll
    for (int j = 0; j < 4; j++) acc[i][j] = zero;

  for (int k0 = 0; k0 < K; k0 += 32) {
#pragma unroll
    for (int r = 0; r < 2; r++) {
      int s = tid + r * 256;
      int row = s >> 2, kc = (s & 3) * 8;
      __builtin_amdgcn_global_load_lds(
          (const __attribute__((address_space(1))) unsigned*)(Ag + (size_t)row * K + k0 + kc),
          (__attribute__((address_space(3))) unsigned*)(As + s * 8), 16, 0, 0);
      __builtin_amdgcn_global_load_lds(
          (const __attribute__((address_space(1))) unsigned*)(Bg + (size_t)row * K + k0 + kc),
          (__attribute__((address_space(3))) unsigned*)(Bs + s * 8), 16, 0, 0);
    }
    __syncthreads();
    short8 a[4], b[4];
#pragma unroll
    for (int i = 0; i < 4; i++)
      a[i] = *(const short8*)(As + ((wm * 64 + i * 16 + ml) * 32 + quad * 8));
#pragma unroll
    for (int j = 0; j < 4; j++)
      b[j] = *(const short8*)(Bs + ((wn * 64 + j * 16 + ml) * 32 + quad * 8));
#pragma unroll
    for (int i = 0; i < 4; i++)
#pragma unroll
      for (int j = 0; j < 4; j++)
        acc[i][j] = __builtin_amdgcn_mfma_f32_16x16x32_bf16(a[i], b[j], acc[i][j], 0, 0, 0);
    __syncthreads();
  }
#pragma unroll
  for (int i = 0; i < 4; i++) {
#pragma unroll
    for (int j = 0; j < 4; j++) {
#pragma unroll
      for (int r = 0; r < 4; r++) {
        int row = bm + wm * 64 + i * 16 + quad * 4 + r;
        int col = bn + wn * 64 + j * 16 + ml;
        size_t idx = (crow0 + row) * (size_t)N + col;
        float v = acc[i][j][r];
        if (OUTBF16) {
          ((u16*)Cv)[idx] = f2bf(v);
        } else {
          if (addend) v += addend[idx];
          ((float*)Cv)[idx] = v;
        }
      }
    }
  }
}

// ---------------- RoPE in-place (fp32 qkv) ----------------
__global__ void rope_kernel(float* __restrict__ qkv, const float* __restrict__ freqs) {
  int s = blockIdx.x;
  for (int t = threadIdx.x; t < (NH + NKVH) * 32; t += 256) {
    int hh = t >> 5, i = t & 31;
    int col = (hh < NH) ? hh * HDIM : DD + (hh - NH) * HDIM;
    float* p = qkv + (size_t)s * QKVN + col + 2 * i;
    float c = freqs[(s * 32 + i) * 2];
    float sn = freqs[(s * 32 + i) * 2 + 1];
    float x0 = p[0], x1 = p[1];
    p[0] = x0 * c - x1 * sn;
    p[1] = x1 * c + x0 * sn;
  }
}

// ---------------- Attention: wave per (head, q-row), online softmax, bf16 out ----------------
__global__ __launch_bounds__(64) void attn_kernel(const float* __restrict__ qkv,
                                                  u16* __restrict__ y) {
  int qrow = blockIdx.x;
  int h = blockIdx.y;
  int lane = threadIdx.x;
  int kvh = h >> 2;
  float qd = qkv[(size_t)qrow * QKVN + h * HDIM + lane];
  const float* kbase = qkv + DD + kvh * HDIM + lane;
  const float* vbase = qkv + DD + NKVH * HDIM + kvh * HDIM + lane;
  float m = -1e30f, l = 0.f, acc = 0.f;
  for (int j = 0; j <= qrow; j++) {
    float kv = kbase[(size_t)j * QKVN];
    float s = qd * kv;
    for (int o = 32; o > 0; o >>= 1) s += __shfl_xor(s, o);
    s *= 0.125f;
    float mn = fmaxf(m, s);
    float alpha = __expf(m - mn);
    float p = __expf(s - mn);
    float vv = vbase[(size_t)j * QKVN];
    l = l * alpha + p;
    acc = acc * alpha + p * vv;
    m = mn;
  }
  y[(size_t)qrow * DD + h * HDIM + lane] = f2bf(acc / l);
}

// ---------------- Gate ----------------
__global__ __launch_bounds__(64) void gate_kernel(const float* __restrict__ hf,
                                                  const float* __restrict__ gw,
                                                  int* __restrict__ ei, float* __restrict__ ew,
                                                  int* __restrict__ cnt) {
  int t = blockIdx.x;
  int lane = threadIdx.x;
  const float* xr = hf + (size_t)t * DD;
  float acc[NE] = {};
  for (int c = 0; c < DD / 64; c++) {
    float xv = xr[lane + 64 * c];
#pragma unroll
    for (int e = 0; e < NE; e++) acc[e] += xv * gw[e * DD + lane + 64 * c];
  }
#pragma unroll
  for (int e = 0; e < NE; e++)
    for (int o = 32; o > 0; o >>= 1) acc[e] += __shfl_xor(acc[e], o);
  if (lane == 0) {
    float mx = acc[0];
    for (int e = 1; e < NE; e++) mx = fmaxf(mx, acc[e]);
    float p[NE], sum = 0.f;
    for (int e = 0; e < NE; e++) { p[e] = __expf(acc[e] - mx); sum += p[e]; }
    for (int e = 0; e < NE; e++) p[e] /= sum;
    int i0 = 0;
    for (int e = 1; e < NE; e++) if (p[e] > p[i0]) i0 = e;
    int i1 = (i0 == 0) ? 1 : 0;
    for (int e = 0; e < NE; e++) if (e != i0 && p[e] > p[i1]) i1 = e;
    float w0 = p[i0], w1 = p[i1], s = w0 + w1;
    ei[t * 2] = i0; ei[t * 2 + 1] = i1;
    ew[t * 2] = w0 / s; ew[t * 2 + 1] = w1 / s;
    atomicAdd(&cnt[i0], 1);
    atomicAdd(&cnt[i1], 1);
  }
}

__global__ void zero_cnt_kernel(int* cnt) {
  if (threadIdx.x < NE) cnt[threadIdx.x] = 0;
}

// padded (128-aligned) per-expert offsets
__global__ void prefix_kernel(const int* __restrict__ cnt, int* __restrict__ poff,
                              int* __restrict__ fill) {
  if (threadIdx.x == 0) {
    int pacc = 0;
    for (int e = 0; e < NE; e++) {
      poff[e] = pacc;
      pacc += (cnt[e] + 127) & ~127;
    }
    poff[NE] = pacc;
  }
  if (threadIdx.x < NE) fill[threadIdx.x] = 0;
}

__global__ void fill_kernel(const int* __restrict__ ei, const int* __restrict__ poff,
                            int* __restrict__ fill, int* __restrict__ slot_of) {
  int t = blockIdx.x * blockDim.x + threadIdx.x;
  if (t >= SS) return;
  for (int a = 0; a < 2; a++) {
    int e = ei[t * 2 + a];
    int pos = atomicAdd(&fill[e], 1);
    slot_of[t * 2 + a] = poff[e] + pos;
  }
}

// gather hf(bf16) rows into padded slot order
__global__ void gather_kernel(const u16* __restrict__ hf16, const int* __restrict__ slot_of,
                              u16* __restrict__ xslot) {
  int t = blockIdx.x;
  uint2 v = ((const uint2*)(hf16 + (size_t)t * DD))[threadIdx.x];
  for (int a = 0; a < 2; a++) {
    int slot = slot_of[t * 2 + a];
    ((uint2*)(xslot + (size_t)slot * DD))[threadIdx.x] = v;
  }
}

// x13 = silu(x1) * x3 (bf16, in-place into x1)
__global__ void silumul_kernel(u16* __restrict__ x1, const u16* __restrict__ x3, int n4) {
  int i = blockIdx.x * 256 + threadIdx.x;
  if (i >= n4) return;
  ushort4 a = ((const ushort4*)x1)[i];
  ushort4 b = ((const ushort4*)x3)[i];
  float f, g;
  ushort4 o;
  f = bf2f(a.x); g = bf2f(b.x); o.x = f2bf(f / (1.f + __expf(-f)) * g);
  f = bf2f(a.y); g = bf2f(b.y); o.y = f2bf(f / (1.f + __expf(-f)) * g);
  f = bf2f(a.z); g = bf2f(b.z); o.z = f2bf(f / (1.f + __expf(-f)) * g);
  f = bf2f(a.w); g = bf2f(b.w); o.w = f2bf(f / (1.f + __expf(-f)) * g);
  ((ushort4*)x1)[i] = o;
}

// out = h + w0*oslot[s0] + w1*oslot[s1]
__global__ void final_kernel(const float* __restrict__ h, const float* __restrict__ oslot,
                             const int* __restrict__ slot_of, const float* __restrict__ ew,
                             float* __restrict__ out) {
  int t = blockIdx.x;
  int s0 = slot_of[t * 2], s1 = slot_of[t * 2 + 1];
  float w0 = ew[t * 2], w1 = ew[t * 2 + 1];
  float4 hv = ((const float4*)(h + (size_t)t * DD))[threadIdx.x];
  float4 a = ((const float4*)(oslot + (size_t)s0 * DD))[threadIdx.x];
  float4 b = ((const float4*)(oslot + (size_t)s1 * DD))[threadIdx.x];
  float4 o;
  o.x = hv.x + w0 * a.x + w1 * b.x;
  o.y = hv.y + w0 * a.y + w1 * b.y;
  o.z = hv.z + w0 * a.z + w1 * b.z;
  o.w = hv.w + w0 * a.w + w1 * b.w;
  ((float4*)(out + (size_t)t * DD))[threadIdx.x] = o;
}

extern "C" void kernel_launch(void* const* d_in, const int* in_sizes, int n_in,
                              void* d_out, int out_size, void* d_ws, size_t ws_size,
                              hipStream_t stream) {
  const float* x = (const float*)d_in[0];
  const float* wqkv = (const float*)d_in[1];
  const float* wo = (const float*)d_in[2];
  const float* gate_w = (const float*)d_in[3];
  const float* w1 = (const float*)d_in[4];
  const float* w2 = (const float*)d_in[5];
  const float* w3 = (const float*)d_in[6];
  const float* attn_norm_w = (const float*)d_in[7];
  const float* ffn_norm_w = (const float*)d_in[8];
  const float* freqs = (const float*)d_in[9];
  float* out = (float*)d_out;

  char* ws = (char*)d_ws;
  size_t off = 0;
  auto alloc = [&](size_t bytes) -> char* {
    char* p = ws + off;
    off = (off + bytes + 255) & ~(size_t)255;
    return p;
  };
  u16* hn16    = (u16*)alloc((size_t)SS * DD * 2);
  float* qkv   = (float*)alloc((size_t)SS * QKVN * 4);
  u16* y16     = (u16*)alloc((size_t)SS * DD * 2);
  float* hbuf  = (float*)alloc((size_t)SS * DD * 4);
  float* hf    = (float*)alloc((size_t)SS * DD * 4);
  u16* hf16    = (u16*)alloc((size_t)SS * DD * 2);
  u16* wqkv16  = (u16*)alloc((size_t)QKVN * DD * 2);
  u16* wo16    = (u16*)alloc((size_t)DD * DD * 2);
  u16* w1_16   = (u16*)alloc((size_t)NE * NI * DD * 2);
  u16* w3_16   = (u16*)alloc((size_t)NE * NI * DD * 2);
  u16* w2_16   = (u16*)alloc((size_t)NE * DD * NI * 2);
  u16* xslot   = (u16*)alloc((size_t)PCAP * DD * 2);
  u16* x1buf   = (u16*)alloc((size_t)PCAP * NI * 2);  // later aliased as x13
  u16* x3buf   = (u16*)alloc((size_t)PCAP * NI * 2);  // later aliased as oslot(fp32)
  int* ei      = (int*)alloc((size_t)SS * 2 * 4);
  float* ew    = (float*)alloc((size_t)SS * 2 * 4);
  int* slot_of = (int*)alloc((size_t)SS * 2 * 4);
  int* cnt     = (int*)alloc(NE * 4);
  int* poff    = (int*)alloc((NE + 1) * 4);
  int* fill    = (int*)alloc(NE * 4);
  float* oslot = (float*)x3buf;  // 20.97MB needed <= 36.7MB available

  auto conv = [&](const float* src, u16* dst, size_t n) {
    int n4 = (int)(n / 4);
    f32_to_bf16_kernel<<<(n4 + 255) / 256, 256, 0, stream>>>(src, dst, n4);
  };

  zero_cnt_kernel<<<1, 64, 0, stream>>>(cnt);
  // weight conversions
  conv(wqkv, wqkv16, (size_t)QKVN * DD);
  conv(wo, wo16, (size_t)DD * DD);
  conv(w1, w1_16, (size_t)NE * NI * DD);
  conv(w3, w3_16, (size_t)NE * NI * DD);
  conv(w2, w2_16, (size_t)NE * DD * NI);

  // ---- attention path ----
  rmsnorm_kernel<<<SS, 256, 0, stream>>>(x, attn_norm_w, nullptr, hn16);
  gemm128<false><<<dim3(SS / 128, QKVN / 128, 1), 256, 0, stream>>>(
      hn16, wqkv16, qkv, nullptr, QKVN, DD, nullptr, 0);
  rope_kernel<<<SS, 256, 0, stream>>>(qkv, freqs);
  attn_kernel<<<dim3(SS, NH), 64, 0, stream>>>(qkv, y16);
  gemm128<false><<<dim3(SS / 128, DD / 128, 1), 256, 0, stream>>>(
      y16, wo16, hbuf, x, DD, DD, nullptr, 0);

  // ---- MoE path ----
  rmsnorm_kernel<<<SS, 256, 0, stream>>>(hbuf, ffn_norm_w, hf, hf16);
  gate_kernel<<<SS, 64, 0, stream>>>(hf, gate_w, ei, ew, cnt);
  prefix_kernel<<<1, 64, 0, stream>>>(cnt, poff, fill);
  fill_kernel<<<(SS + 255) / 256, 256, 0, stream>>>(ei, poff, fill, slot_of);
  gather_kernel<<<SS, 256, 0, stream>>>(hf16, slot_of, xslot);
  // stage 1: x1 = xslot @ w1^T, x3 = xslot @ w3^T (bf16 out)
  gemm128<true><<<dim3(16, NI / 128, NE), 256, 0, stream>>>(
      xslot, w1_16, x1buf, nullptr, NI, DD, poff, (long long)NI * DD);
  gemm128<true><<<dim3(16, NI / 128, NE), 256, 0, stream>>>(
      xslot, w3_16, x3buf, nullptr, NI, DD, poff, (long long)NI * DD);
  {
    int n4 = (int)((size_t)PCAP * NI / 4);
    silumul_kernel<<<(n4 + 255) / 256, 256, 0, stream>>>(x1buf, x3buf, n4);
  }
  // stage 2: oslot = x13 @ w2^T (fp32 out) — x13 lives in x1buf, oslot in x3buf
  gemm128<false><<<dim3(16, DD / 128, NE), 256, 0, stream>>>(
      x1buf, w2_16, oslot, nullptr, DD, NI, poff, (long long)DD * NI);
  final_kernel<<<SS, 256, 0, stream>>>(hbuf, oslot, slot_of, ew, out);
}

// Round 3
// 989.012 us; speedup vs baseline: 10.1059x; 3.7151x over previous
//
#include <hip/hip_runtime.h>
#include <hip/hip_bf16.h>
#include <math.h>

#define SS 2048
#define DD 1024
#define NH 16
#define NKVH 4
#define HDIM 64
#define NE 8
#define NI 3584
#define QKVN 1536
#define PCAP 5120

typedef unsigned short u16;
typedef short short8 __attribute__((ext_vector_type(8)));
typedef float floatx4 __attribute__((ext_vector_type(4)));

__device__ inline u16 f2bf(float f) {
  unsigned u = __float_as_uint(f);
  unsigned r = u + 0x7fffu + ((u >> 16) & 1u);
  return (u16)(r >> 16);
}
__device__ inline float bf2f(u16 h) { return __uint_as_float((unsigned)h << 16); }

// ---------------- fp32 -> bf16 bulk convert ----------------
__global__ void f32_to_bf16_kernel(const float* __restrict__ in, u16* __restrict__ out, int n4) {
  int i = blockIdx.x * 256 + threadIdx.x;
  if (i >= n4) return;
  float4 v = ((const float4*)in)[i];
  ((ushort4*)out)[i] = make_ushort4(f2bf(v.x), f2bf(v.y), f2bf(v.z), f2bf(v.w));
}

// ---------------- RMSNorm ----------------
__global__ void rmsnorm_kernel(const float* __restrict__ x, const float* __restrict__ w,
                               float* __restrict__ o32, u16* __restrict__ o16) {
  int row = blockIdx.x;
  int t = threadIdx.x;
  float4 v = ((const float4*)(x + (size_t)row * DD))[t];
  float ss = v.x * v.x + v.y * v.y + v.z * v.z + v.w * v.w;
  for (int o = 32; o > 0; o >>= 1) ss += __shfl_xor(ss, o);
  __shared__ float red[4];
  if ((t & 63) == 0) red[t >> 6] = ss;
  __syncthreads();
  float tot = red[0] + red[1] + red[2] + red[3];
  float r = rsqrtf(tot * (1.f / DD) + 1e-5f);
  float4 wv = ((const float4*)w)[t];
  float4 o;
  o.x = v.x * r * wv.x; o.y = v.y * r * wv.y; o.z = v.z * r * wv.z; o.w = v.w * r * wv.w;
  if (o32) ((float4*)(o32 + (size_t)row * DD))[t] = o;
  if (o16) ((ushort4*)(o16 + (size_t)row * DD))[t] =
      make_ushort4(f2bf(o.x), f2bf(o.y), f2bf(o.z), f2bf(o.w));
}

// ---------------- MFMA GEMM (m97 structure) ----------------
template <bool OUTBF16>
__global__ __launch_bounds__(256) void gemm128(
    const u16* __restrict__ A, const u16* __restrict__ B,
    void* __restrict__ Cv, const float* __restrict__ addend,
    int N, int K, const int* __restrict__ poff, long long bstride) {
  __shared__ u16 As[128 * 32];
  __shared__ u16 Bs[128 * 32];
  int tid = threadIdx.x;
  int bm = blockIdx.x * 128;
  int bn = blockIdx.y * 128;
  size_t crow0 = 0;
  if (poff) {
    int e = blockIdx.z;
    int off = poff[e];
    int pcnt = poff[e + 1] - off;
    if (bm >= pcnt) return;
    A += (size_t)off * K;
    crow0 = (size_t)off;
    B += (size_t)e * bstride;
  }
  const u16* Ag = A + (size_t)bm * K;
  const u16* Bg = B + (size_t)bn * K;
  int wave = tid >> 6, lane = tid & 63;
  int wm = wave >> 1, wn = wave & 1;
  int ml = lane & 15, quad = lane >> 4;

  floatx4 zero = {0.f, 0.f, 0.f, 0.f};
  floatx4 acc[4][4];
#pragma unroll
  for (int i = 0; i < 4; i++)
#pragma unroll
    for (int j = 0; j < 4; j++) acc[i][j] = zero;

  for (int k0 = 0; k0 < K; k0 += 32) {
#pragma unroll
    for (int r = 0; r < 2; r++) {
      int s = tid + r * 256;
      int row = s >> 2, kc = (s & 3) * 8;
      __builtin_amdgcn_global_load_lds(
          (const __attribute__((address_space(1))) unsigned*)(Ag + (size_t)row * K + k0 + kc),
          (__attribute__((address_space(3))) unsigned*)(As + s * 8), 16, 0, 0);
      __builtin_amdgcn_global_load_lds(
          (const __attribute__((address_space(1))) unsigned*)(Bg + (size_t)row * K + k0 + kc),
          (__attribute__((address_space(3))) unsigned*)(Bs + s * 8), 16, 0, 0);
    }
    __syncthreads();
    short8 a[4], b[4];
#pragma unroll
    for (int i = 0; i < 4; i++)
      a[i] = *(const short8*)(As + ((wm * 64 + i * 16 + ml) * 32 + quad * 8));
#pragma unroll
    for (int j = 0; j < 4; j++)
      b[j] = *(const short8*)(Bs + ((wn * 64 + j * 16 + ml) * 32 + quad * 8));
#pragma unroll
    for (int i = 0; i < 4; i++)
#pragma unroll
      for (int j = 0; j < 4; j++)
        acc[i][j] = __builtin_amdgcn_mfma_f32_16x16x32_bf16(a[i], b[j], acc[i][j], 0, 0, 0);
    __syncthreads();
  }
#pragma unroll
  for (int i = 0; i < 4; i++) {
#pragma unroll
    for (int j = 0; j < 4; j++) {
#pragma unroll
      for (int r = 0; r < 4; r++) {
        int row = bm + wm * 64 + i * 16 + quad * 4 + r;
        int col = bn + wn * 64 + j * 16 + ml;
        size_t idx = (crow0 + row) * (size_t)N + col;
        float v = acc[i][j][r];
        if (OUTBF16) {
          ((u16*)Cv)[idx] = f2bf(v);
        } else {
          if (addend) v += addend[idx];
          ((float*)Cv)[idx] = v;
        }
      }
    }
  }
}

// ---------------- RoPE: fp32 qkv -> bf16 qT [NH][S][64] (scaled 1/8), kT [NKVH][S][64] ----------------
__global__ void rope_kernel(const float* __restrict__ qkv, const float* __restrict__ freqs,
                            u16* __restrict__ qT, u16* __restrict__ kT) {
  int s = blockIdx.x;
  int tid = threadIdx.x;
#pragma unroll
  for (int r = 0; r < 2; r++) {
    int tt = r * 256 + tid;
    int hh = tt >> 5, i = tt & 31;
    const float* p = qkv + (size_t)s * QKVN + hh * 64 + 2 * i;
    float c = freqs[(s * 32 + i) * 2], sn = freqs[(s * 32 + i) * 2 + 1];
    float x0 = p[0], x1 = p[1];
    float r0 = (x0 * c - x1 * sn) * 0.125f;
    float r1 = (x1 * c + x0 * sn) * 0.125f;
    unsigned pk = (unsigned)f2bf(r0) | ((unsigned)f2bf(r1) << 16);
    *(unsigned*)(qT + ((size_t)hh * SS + s) * 64 + 2 * i) = pk;
  }
  if (tid < 128) {
    int hh = tid >> 5, i = tid & 31;
    const float* p = qkv + (size_t)s * QKVN + DD + hh * 64 + 2 * i;
    float c = freqs[(s * 32 + i) * 2], sn = freqs[(s * 32 + i) * 2 + 1];
    float x0 = p[0], x1 = p[1];
    float r0 = x0 * c - x1 * sn;
    float r1 = x1 * c + x0 * sn;
    unsigned pk = (unsigned)f2bf(r0) | ((unsigned)f2bf(r1) << 16);
    *(unsigned*)(kT + ((size_t)hh * SS + s) * 64 + 2 * i) = pk;
  }
}

// ---------------- V transpose: qkv v-part -> vT2 [NKVH*64][S] bf16 ----------------
__global__ void vtrans_kernel(const float* __restrict__ qkv, u16* __restrict__ vT2) {
  __shared__ u16 tile[64][65];
  int bs = blockIdx.x * 64;   // seq tile
  int bc = blockIdx.y * 64;   // v-col tile (of 256)
  int tid = threadIdx.x;
#pragma unroll
  for (int it = 0; it < 4; it++) {
    int idx = it * 256 + tid;
    int r = idx >> 4, c4 = idx & 15;
    float4 v = *(const float4*)(qkv + (size_t)(bs + r) * QKVN + DD + 256 + bc + c4 * 4);
    tile[r][c4 * 4 + 0] = f2bf(v.x);
    tile[r][c4 * 4 + 1] = f2bf(v.y);
    tile[r][c4 * 4 + 2] = f2bf(v.z);
    tile[r][c4 * 4 + 3] = f2bf(v.w);
  }
  __syncthreads();
#pragma unroll
  for (int it = 0; it < 4; it++) {
    int idx = it * 256 + tid;
    int cc = idx >> 4, s4 = idx & 15;
    ushort4 o = make_ushort4(tile[s4 * 4 + 0][cc], tile[s4 * 4 + 1][cc],
                             tile[s4 * 4 + 2][cc], tile[s4 * 4 + 3][cc]);
    *(ushort4*)(vT2 + (size_t)(bc + cc) * SS + bs + s4 * 4) = o;
  }
}

// ---------------- Flash attention: BQ=128 (4 waves x 32 rows), BKV=64, MFMA ----------------
#define BQ 128
#define BKV 64
__global__ __launch_bounds__(256) void attn_flash(const u16* __restrict__ qT,
                                                  const u16* __restrict__ kT,
                                                  const u16* __restrict__ vT2,
                                                  u16* __restrict__ y) {
  __shared__ u16 Ks[2 * 64 * 32];    // [c][s][32]
  __shared__ u16 Vs[2 * 64 * 32];    // [kc][d][32]
  __shared__ u16 Ps[2 * 128 * 36];   // [colplane][row][36] padded
  int t = blockIdx.x;
  int h = blockIdx.y;
  int kvh = h >> 2;
  int bq = t * BQ;
  int tid = threadIdx.x, wave = tid >> 6, lane = tid & 63;
  int ml = lane & 15, quad = lane >> 4;

  // Q fragments, hoisted for the whole block
  short8 qf[2][2];
#pragma unroll
  for (int i = 0; i < 2; i++)
#pragma unroll
    for (int c = 0; c < 2; c++)
      qf[i][c] = *(const short8*)(qT + ((size_t)h * SS + bq + wave * 32 + i * 16 + ml) * 64 +
                                  c * 32 + quad * 8);

  float m_i[2][4], l_i[2][4];
  floatx4 o_acc[2][4];
#pragma unroll
  for (int i = 0; i < 2; i++)
#pragma unroll
    for (int r = 0; r < 4; r++) {
      m_i[i][r] = -1e30f;
      l_i[i][r] = 0.f;
      o_acc[i][r] = (floatx4){0.f, 0.f, 0.f, 0.f};
    }

  int nkv = 2 * t + 2;
  for (int kt = 0; kt < nkv; kt++) {
    int bk = kt * BKV;
    __syncthreads();
    // stage K, V: 512 chunks each, 2 per thread
#pragma unroll
    for (int r = 0; r < 2; r++) {
      int ch = r * 256 + tid;
      int c = ch >> 8, srow = (ch >> 2) & 63, o8 = ch & 3;
      __builtin_amdgcn_global_load_lds(
          (const __attribute__((address_space(1))) unsigned*)(
              kT + ((size_t)kvh * SS + bk + srow) * 64 + c * 32 + o8 * 8),
          (__attribute__((address_space(3))) unsigned*)(Ks + ch * 8), 16, 0, 0);
      __builtin_amdgcn_global_load_lds(
          (const __attribute__((address_space(1))) unsigned*)(
              vT2 + ((size_t)kvh * 64 + srow) * SS + bk + c * 32 + o8 * 8),
          (__attribute__((address_space(3))) unsigned*)(Vs + ch * 8), 16, 0, 0);
    }
    __syncthreads();

    // S = Q K^T  (per wave: 32 q-rows x 64 kv)
    floatx4 s_acc[2][4];
#pragma unroll
    for (int i = 0; i < 2; i++)
#pragma unroll
      for (int j = 0; j < 4; j++) s_acc[i][j] = (floatx4){0.f, 0.f, 0.f, 0.f};
#pragma unroll
    for (int c = 0; c < 2; c++) {
#pragma unroll
      for (int jk = 0; jk < 4; jk++) {
        short8 kf = *(const short8*)(Ks + c * 2048 + (jk * 16 + ml) * 32 + quad * 8);
#pragma unroll
        for (int i = 0; i < 2; i++)
          s_acc[i][jk] = __builtin_amdgcn_mfma_f32_16x16x32_bf16(qf[i][c], kf, s_acc[i][jk], 0, 0, 0);
      }
    }
    // causal mask (only tiles overlapping the diagonal)
    if (bk + BKV - 1 > bq) {
#pragma unroll
      for (int i = 0; i < 2; i++)
#pragma unroll
        for (int jk = 0; jk < 4; jk++)
#pragma unroll
          for (int r = 0; r < 4; r++) {
            int row = bq + wave * 32 + i * 16 + quad * 4 + r;
            int col = bk + jk * 16 + ml;
            if (col > row) s_acc[i][jk][r] = -1e30f;
          }
    }
    // online softmax (row lives across the 16-lane ml group)
#pragma unroll
    for (int i = 0; i < 2; i++) {
#pragma unroll
      for (int r = 0; r < 4; r++) {
        float mx = -1e30f;
#pragma unroll
        for (int jk = 0; jk < 4; jk++) mx = fmaxf(mx, s_acc[i][jk][r]);
        for (int o = 1; o < 16; o <<= 1) mx = fmaxf(mx, __shfl_xor(mx, o));
        float mnew = fmaxf(m_i[i][r], mx);
        float alpha = __expf(m_i[i][r] - mnew);
        m_i[i][r] = mnew;
        float rs = 0.f;
#pragma unroll
        for (int jk = 0; jk < 4; jk++) {
          float p = __expf(s_acc[i][jk][r] - mnew);
          s_acc[i][jk][r] = p;
          rs += p;
        }
        for (int o = 1; o < 16; o <<= 1) rs += __shfl_xor(rs, o);
        l_i[i][r] = l_i[i][r] * alpha + rs;
#pragma unroll
        for (int jd = 0; jd < 4; jd++) o_acc[i][jd][r] *= alpha;
      }
    }
    // write P to LDS (own strip only; no barrier needed)
#pragma unroll
    for (int i = 0; i < 2; i++)
#pragma unroll
      for (int jk = 0; jk < 4; jk++)
#pragma unroll
        for (int r = 0; r < 4; r++) {
          int row = wave * 32 + i * 16 + quad * 4 + r;
          int col = jk * 16 + ml;
          Ps[(col >> 5) * (128 * 36) + row * 36 + (col & 31)] = f2bf(s_acc[i][jk][r]);
        }
    // O += P V
#pragma unroll
    for (int kc = 0; kc < 2; kc++) {
      short8 pf[2];
#pragma unroll
      for (int i = 0; i < 2; i++)
        pf[i] = *(const short8*)(Ps + kc * (128 * 36) + (wave * 32 + i * 16 + ml) * 36 + quad * 8);
#pragma unroll
      for (int jd = 0; jd < 4; jd++) {
        short8 vf = *(const short8*)(Vs + kc * 2048 + (jd * 16 + ml) * 32 + quad * 8);
#pragma unroll
        for (int i = 0; i < 2; i++)
          o_acc[i][jd] = __builtin_amdgcn_mfma_f32_16x16x32_bf16(pf[i], vf, o_acc[i][jd], 0, 0, 0);
      }
    }
  }
  // epilogue
#pragma unroll
  for (int i = 0; i < 2; i++) {
    float inv[4];
#pragma unroll
    for (int r = 0; r < 4; r++) inv[r] = 1.f / l_i[i][r];
#pragma unroll
    for (int jd = 0; jd < 4; jd++)
#pragma unroll
      for (int r = 0; r < 4; r++) {
        int row = bq + wave * 32 + i * 16 + quad * 4 + r;
        int col = h * 64 + jd * 16 + ml;
        y[(size_t)row * DD + col] = f2bf(o_acc[i][jd][r] * inv[r]);
      }
  }
}

// ---------------- Gate ----------------
__global__ __launch_bounds__(64) void gate_kernel(const float* __restrict__ hf,
                                                  const float* __restrict__ gw,
                                                  int* __restrict__ ei, float* __restrict__ ew,
                                                  int* __restrict__ cnt) {
  int t = blockIdx.x;
  int lane = threadIdx.x;
  const float* xr = hf + (size_t)t * DD;
  float acc[NE] = {};
  for (int c = 0; c < DD / 64; c++) {
    float xv = xr[lane + 64 * c];
#pragma unroll
    for (int e = 0; e < NE; e++) acc[e] += xv * gw[e * DD + lane + 64 * c];
  }
#pragma unroll
  for (int e = 0; e < NE; e++)
    for (int o = 32; o > 0; o >>= 1) acc[e] += __shfl_xor(acc[e], o);
  if (lane == 0) {
    float mx = acc[0];
    for (int e = 1; e < NE; e++) mx = fmaxf(mx, acc[e]);
    float p[NE], sum = 0.f;
    for (int e = 0; e < NE; e++) { p[e] = __expf(acc[e] - mx); sum += p[e]; }
    for (int e = 0; e < NE; e++) p[e] /= sum;
    int i0 = 0;
    for (int e = 1; e < NE; e++) if (p[e] > p[i0]) i0 = e;
    int i1 = (i0 == 0) ? 1 : 0;
    for (int e = 0; e < NE; e++) if (e != i0 && p[e] > p[i1]) i1 = e;
    float w0 = p[i0], w1 = p[i1], s = w0 + w1;
    ei[t * 2] = i0; ei[t * 2 + 1] = i1;
    ew[t * 2] = w0 / s; ew[t * 2 + 1] = w1 / s;
    atomicAdd(&cnt[i0], 1);
    atomicAdd(&cnt[i1], 1);
  }
}

__global__ void zero_cnt_kernel(int* cnt) {
  if (threadIdx.x < NE) cnt[threadIdx.x] = 0;
}

__global__ void prefix_kernel(const int* __restrict__ cnt, int* __restrict__ poff,
                              int* __restrict__ fill) {
  if (threadIdx.x == 0) {
    int pacc = 0;
    for (int e = 0; e < NE; e++) {
      poff[e] = pacc;
      pacc += (cnt[e] + 127) & ~127;
    }
    poff[NE] = pacc;
  }
  if (threadIdx.x < NE) fill[threadIdx.x] = 0;
}

__global__ void fill_kernel(const int* __restrict__ ei, const int* __restrict__ poff,
                            int* __restrict__ fill, int* __restrict__ slot_of) {
  int t = blockIdx.x * blockDim.x + threadIdx.x;
  if (t >= SS) return;
  for (int a = 0; a < 2; a++) {
    int e = ei[t * 2 + a];
    int pos = atomicAdd(&fill[e], 1);
    slot_of[t * 2 + a] = poff[e] + pos;
  }
}

__global__ void gather_kernel(const u16* __restrict__ hf16, const int* __restrict__ slot_of,
                              u16* __restrict__ xslot) {
  int t = blockIdx.x;
  uint2 v = ((const uint2*)(hf16 + (size_t)t * DD))[threadIdx.x];
  for (int a = 0; a < 2; a++) {
    int slot = slot_of[t * 2 + a];
    ((uint2*)(xslot + (size_t)slot * DD))[threadIdx.x] = v;
  }
}

__global__ void silumul_kernel(u16* __restrict__ x1, const u16* __restrict__ x3, int n4) {
  int i = blockIdx.x * 256 + threadIdx.x;
  if (i >= n4) return;
  ushort4 a = ((const ushort4*)x1)[i];
  ushort4 b = ((const ushort4*)x3)[i];
  float f, g;
  ushort4 o;
  f = bf2f(a.x); g = bf2f(b.x); o.x = f2bf(f / (1.f + __expf(-f)) * g);
  f = bf2f(a.y); g = bf2f(b.y); o.y = f2bf(f / (1.f + __expf(-f)) * g);
  f = bf2f(a.z); g = bf2f(b.z); o.z = f2bf(f / (1.f + __expf(-f)) * g);
  f = bf2f(a.w); g = bf2f(b.w); o.w = f2bf(f / (1.f + __expf(-f)) * g);
  ((ushort4*)x1)[i] = o;
}

__global__ void final_kernel(const float* __restrict__ h, const float* __restrict__ oslot,
                             const int* __restrict__ slot_of, const float* __restrict__ ew,
                             float* __restrict__ out) {
  int t = blockIdx.x;
  int s0 = slot_of[t * 2], s1 = slot_of[t * 2 + 1];
  float w0 = ew[t * 2], w1 = ew[t * 2 + 1];
  float4 hv = ((const float4*)(h + (size_t)t * DD))[threadIdx.x];
  float4 a = ((const float4*)(oslot + (size_t)s0 * DD))[threadIdx.x];
  float4 b = ((const float4*)(oslot + (size_t)s1 * DD))[threadIdx.x];
  float4 o;
  o.x = hv.x + w0 * a.x + w1 * b.x;
  o.y = hv.y + w0 * a.y + w1 * b.y;
  o.z = hv.z + w0 * a.z + w1 * b.z;
  o.w = hv.w + w0 * a.w + w1 * b.w;
  ((float4*)(out + (size_t)t * DD))[threadIdx.x] = o;
}

extern "C" void kernel_launch(void* const* d_in, const int* in_sizes, int n_in,
                              void* d_out, int out_size, void* d_ws, size_t ws_size,
                              hipStream_t stream) {
  const float* x = (const float*)d_in[0];
  const float* wqkv = (const float*)d_in[1];
  const float* wo = (const float*)d_in[2];
  const float* gate_w = (const float*)d_in[3];
  const float* w1 = (const float*)d_in[4];
  const float* w2 = (const float*)d_in[5];
  const float* w3 = (const float*)d_in[6];
  const float* attn_norm_w = (const float*)d_in[7];
  const float* ffn_norm_w = (const float*)d_in[8];
  const float* freqs = (const float*)d_in[9];
  float* out = (float*)d_out;

  char* ws = (char*)d_ws;
  size_t off = 0;
  auto alloc = [&](size_t bytes) -> char* {
    char* p = ws + off;
    off = (off + bytes + 255) & ~(size_t)255;
    return p;
  };
  u16* hn16    = (u16*)alloc((size_t)SS * DD * 2);   // aliased as qT after qkv GEMM
  float* qkv   = (float*)alloc((size_t)SS * QKVN * 4);
  u16* y16     = (u16*)alloc((size_t)SS * DD * 2);
  float* hbuf  = (float*)alloc((size_t)SS * DD * 4);
  float* hf    = (float*)alloc((size_t)SS * DD * 4);
  u16* hf16    = (u16*)alloc((size_t)SS * DD * 2);
  u16* kT      = (u16*)alloc((size_t)NKVH * SS * HDIM * 2);
  u16* vT2     = (u16*)alloc((size_t)NKVH * HDIM * SS * 2);
  u16* wqkv16  = (u16*)alloc((size_t)QKVN * DD * 2);
  u16* wo16    = (u16*)alloc((size_t)DD * DD * 2);
  u16* w1_16   = (u16*)alloc((size_t)NE * NI * DD * 2);
  u16* w3_16   = (u16*)alloc((size_t)NE * NI * DD * 2);
  u16* w2_16   = (u16*)alloc((size_t)NE * DD * NI * 2);
  u16* xslot   = (u16*)alloc((size_t)PCAP * DD * 2);
  u16* x1buf   = (u16*)alloc((size_t)PCAP * NI * 2);
  u16* x3buf   = (u16*)alloc((size_t)PCAP * NI * 2);
  int* ei      = (int*)alloc((size_t)SS * 2 * 4);
  float* ew    = (float*)alloc((size_t)SS * 2 * 4);
  int* slot_of = (int*)alloc((size_t)SS * 2 * 4);
  int* cnt     = (int*)alloc(NE * 4);
  int* poff    = (int*)alloc((NE + 1) * 4);
  int* fill    = (int*)alloc(NE * 4);
  u16* qT      = hn16;           // [NH][SS][64] = 4MB, reuse hn16 (done after qkv GEMM)
  float* oslot = (float*)x3buf;  // stage2 output aliases x3buf

  auto conv = [&](const float* src, u16* dst, size_t n) {
    int n4 = (int)(n / 4);
    f32_to_bf16_kernel<<<(n4 + 255) / 256, 256, 0, stream>>>(src, dst, n4);
  };

  zero_cnt_kernel<<<1, 64, 0, stream>>>(cnt);
  conv(wqkv, wqkv16, (size_t)QKVN * DD);
  conv(wo, wo16, (size_t)DD * DD);
  conv(w1, w1_16, (size_t)NE * NI * DD);
  conv(w3, w3_16, (size_t)NE * NI * DD);
  conv(w2, w2_16, (size_t)NE * DD * NI);

  // ---- attention path ----
  rmsnorm_kernel<<<SS, 256, 0, stream>>>(x, attn_norm_w, nullptr, hn16);
  gemm128<false><<<dim3(SS / 128, QKVN / 128, 1), 256, 0, stream>>>(
      hn16, wqkv16, qkv, nullptr, QKVN, DD, nullptr, 0);
  rope_kernel<<<SS, 256, 0, stream>>>(qkv, freqs, qT, kT);
  vtrans_kernel<<<dim3(SS / 64, 4), 256, 0, stream>>>(qkv, vT2);
  attn_flash<<<dim3(SS / BQ, NH), 256, 0, stream>>>(qT, kT, vT2, y16);
  gemm128<false><<<dim3(SS / 128, DD / 128, 1), 256, 0, stream>>>(
      y16, wo16, hbuf, x, DD, DD, nullptr, 0);

  // ---- MoE path ----
  rmsnorm_kernel<<<SS, 256, 0, stream>>>(hbuf, ffn_norm_w, hf, hf16);
  gate_kernel<<<SS, 64, 0, stream>>>(hf, gate_w, ei, ew, cnt);
  prefix_kernel<<<1, 64, 0, stream>>>(cnt, poff, fill);
  fill_kernel<<<(SS + 255) / 256, 256, 0, stream>>>(ei, poff, fill, slot_of);
  gather_kernel<<<SS, 256, 0, stream>>>(hf16, slot_of, xslot);
  gemm128<true><<<dim3(PCAP / 128, NI / 128, NE), 256, 0, stream>>>(
      xslot, w1_16, x1buf, nullptr, NI, DD, poff, (long long)NI * DD);
  gemm128<true><<<dim3(PCAP / 128, NI / 128, NE), 256, 0, stream>>>(
      xslot, w3_16, x3buf, nullptr, NI, DD, poff, (long long)NI * DD);
  {
    int n4 = (int)((size_t)PCAP * NI / 4);
    silumul_kernel<<<(n4 + 255) / 256, 256, 0, stream>>>(x1buf, x3buf, n4);
  }
  gemm128<false><<<dim3(PCAP / 128, DD / 128, NE), 256, 0, stream>>>(
      x1buf, w2_16, oslot, nullptr, DD, NI, poff, (long long)DD * NI);
  final_kernel<<<SS, 256, 0, stream>>>(hbuf, oslot, slot_of, ew, out);
}

// Round 4
// 888.953 us; speedup vs baseline: 11.2434x; 1.1126x over previous
//
#include <hip/hip_runtime.h>
#include <hip/hip_bf16.h>
#include <math.h>

#define SS 2048
#define DD 1024
#define NH 16
#define NKVH 4
#define HDIM 64
#define NE 8
#define NI 3584
#define QKVN 1536
#define PCAP 5120
#define NTILEMAX 40   // PCAP/128

typedef unsigned short u16;
typedef short short8 __attribute__((ext_vector_type(8)));
typedef float floatx4 __attribute__((ext_vector_type(4)));

__device__ inline u16 f2bf(float f) {
  unsigned u = __float_as_uint(f);
  unsigned r = u + 0x7fffu + ((u >> 16) & 1u);
  return (u16)(r >> 16);
}
__device__ inline float bf2f(u16 h) { return __uint_as_float((unsigned)h << 16); }

// ---------------- fp32 -> bf16 bulk convert ----------------
__global__ void f32_to_bf16_kernel(const float* __restrict__ in, u16* __restrict__ out, int n4) {
  int i = blockIdx.x * 256 + threadIdx.x;
  if (i >= n4) return;
  float4 v = ((const float4*)in)[i];
  ((ushort4*)out)[i] = make_ushort4(f2bf(v.x), f2bf(v.y), f2bf(v.z), f2bf(v.w));
}

// ---------------- RMSNorm ----------------
__global__ void rmsnorm_kernel(const float* __restrict__ x, const float* __restrict__ w,
                               float* __restrict__ o32, u16* __restrict__ o16) {
  int row = blockIdx.x;
  int t = threadIdx.x;
  float4 v = ((const float4*)(x + (size_t)row * DD))[t];
  float ss = v.x * v.x + v.y * v.y + v.z * v.z + v.w * v.w;
  for (int o = 32; o > 0; o >>= 1) ss += __shfl_xor(ss, o);
  __shared__ float red[4];
  if ((t & 63) == 0) red[t >> 6] = ss;
  __syncthreads();
  float tot = red[0] + red[1] + red[2] + red[3];
  float r = rsqrtf(tot * (1.f / DD) + 1e-5f);
  float4 wv = ((const float4*)w)[t];
  float4 o;
  o.x = v.x * r * wv.x; o.y = v.y * r * wv.y; o.z = v.z * r * wv.z; o.w = v.w * r * wv.w;
  if (o32) ((float4*)(o32 + (size_t)row * DD))[t] = o;
  if (o16) ((ushort4*)(o16 + (size_t)row * DD))[t] =
      make_ushort4(f2bf(o.x), f2bf(o.y), f2bf(o.z), f2bf(o.w));
}

// ---------------- Plain MFMA GEMM (qkv, wo): C = A @ B^T (+addend) ----------------
__global__ __launch_bounds__(256) void gemm128(
    const u16* __restrict__ A, const u16* __restrict__ B,
    float* __restrict__ C, const float* __restrict__ addend, int N, int K) {
  __shared__ u16 As[128 * 32];
  __shared__ u16 Bs[128 * 32];
  int tid = threadIdx.x;
  int bm = blockIdx.x * 128;
  int bn = blockIdx.y * 128;
  const u16* Ag = A + (size_t)bm * K;
  const u16* Bg = B + (size_t)bn * K;
  int wave = tid >> 6, lane = tid & 63;
  int wm = wave >> 1, wn = wave & 1;
  int ml = lane & 15, quad = lane >> 4;

  floatx4 acc[4][4];
#pragma unroll
  for (int i = 0; i < 4; i++)
#pragma unroll
    for (int j = 0; j < 4; j++) acc[i][j] = (floatx4){0.f, 0.f, 0.f, 0.f};

  for (int k0 = 0; k0 < K; k0 += 32) {
#pragma unroll
    for (int r = 0; r < 2; r++) {
      int s = tid + r * 256;
      int row = s >> 2, kc = (s & 3) * 8;
      __builtin_amdgcn_global_load_lds(
          (const __attribute__((address_space(1))) unsigned*)(Ag + (size_t)row * K + k0 + kc),
          (__attribute__((address_space(3))) unsigned*)(As + s * 8), 16, 0, 0);
      __builtin_amdgcn_global_load_lds(
          (const __attribute__((address_space(1))) unsigned*)(Bg + (size_t)row * K + k0 + kc),
          (__attribute__((address_space(3))) unsigned*)(Bs + s * 8), 16, 0, 0);
    }
    __syncthreads();
    short8 a[4], b[4];
#pragma unroll
    for (int i = 0; i < 4; i++)
      a[i] = *(const short8*)(As + ((wm * 64 + i * 16 + ml) * 32 + quad * 8));
#pragma unroll
    for (int j = 0; j < 4; j++)
      b[j] = *(const short8*)(Bs + ((wn * 64 + j * 16 + ml) * 32 + quad * 8));
#pragma unroll
    for (int i = 0; i < 4; i++)
#pragma unroll
      for (int j = 0; j < 4; j++)
        acc[i][j] = __builtin_amdgcn_mfma_f32_16x16x32_bf16(a[i], b[j], acc[i][j], 0, 0, 0);
    __syncthreads();
  }
#pragma unroll
  for (int i = 0; i < 4; i++) {
#pragma unroll
    for (int j = 0; j < 4; j++) {
#pragma unroll
      for (int r = 0; r < 4; r++) {
        int row = bm + wm * 64 + i * 16 + quad * 4 + r;
        int col = bn + wn * 64 + j * 16 + ml;
        size_t idx = (size_t)row * N + col;
        float v = acc[i][j][r];
        if (addend) v += addend[idx];
        C[idx] = v;
      }
    }
  }
}

// ---------------- MoE stage 1 fused: x13 = silu(X@w1^T) * (X@w3^T), bf16 out ----------------
__global__ __launch_bounds__(256) void moe_stage1(
    const u16* __restrict__ xslot, const u16* __restrict__ w1b, const u16* __restrict__ w3b,
    const int* __restrict__ tmap, u16* __restrict__ x13) {
  __shared__ u16 As[128 * 32];
  __shared__ u16 B1s[128 * 32];
  __shared__ u16 B3s[128 * 32];
  if ((int)blockIdx.x >= tmap[0]) return;
  int entry = tmap[1 + blockIdx.x];
  int e = entry & 7;
  int row0 = (entry >> 3) * 128;
  int bn = blockIdx.y * 128;
  const u16* Ag = xslot + (size_t)row0 * DD;
  const u16* B1g = w1b + (size_t)e * NI * DD + (size_t)bn * DD;
  const u16* B3g = w3b + (size_t)e * NI * DD + (size_t)bn * DD;
  int tid = threadIdx.x, wave = tid >> 6, lane = tid & 63;
  int wm = wave >> 1, wn = wave & 1;
  int ml = lane & 15, quad = lane >> 4;

  floatx4 acc1[4][4], acc3[4][4];
#pragma unroll
  for (int i = 0; i < 4; i++)
#pragma unroll
    for (int j = 0; j < 4; j++) {
      acc1[i][j] = (floatx4){0.f, 0.f, 0.f, 0.f};
      acc3[i][j] = (floatx4){0.f, 0.f, 0.f, 0.f};
    }

  for (int k0 = 0; k0 < DD; k0 += 32) {
#pragma unroll
    for (int r = 0; r < 2; r++) {
      int s = tid + r * 256;
      int row = s >> 2, kc = (s & 3) * 8;
      __builtin_amdgcn_global_load_lds(
          (const __attribute__((address_space(1))) unsigned*)(Ag + (size_t)row * DD + k0 + kc),
          (__attribute__((address_space(3))) unsigned*)(As + s * 8), 16, 0, 0);
      __builtin_amdgcn_global_load_lds(
          (const __attribute__((address_space(1))) unsigned*)(B1g + (size_t)row * DD + k0 + kc),
          (__attribute__((address_space(3))) unsigned*)(B1s + s * 8), 16, 0, 0);
      __builtin_amdgcn_global_load_lds(
          (const __attribute__((address_space(1))) unsigned*)(B3g + (size_t)row * DD + k0 + kc),
          (__attribute__((address_space(3))) unsigned*)(B3s + s * 8), 16, 0, 0);
    }
    __syncthreads();
    short8 a[4], b1[4], b3[4];
#pragma unroll
    for (int i = 0; i < 4; i++)
      a[i] = *(const short8*)(As + ((wm * 64 + i * 16 + ml) * 32 + quad * 8));
#pragma unroll
    for (int j = 0; j < 4; j++) {
      b1[j] = *(const short8*)(B1s + ((wn * 64 + j * 16 + ml) * 32 + quad * 8));
      b3[j] = *(const short8*)(B3s + ((wn * 64 + j * 16 + ml) * 32 + quad * 8));
    }
#pragma unroll
    for (int i = 0; i < 4; i++)
#pragma unroll
      for (int j = 0; j < 4; j++) {
        acc1[i][j] = __builtin_amdgcn_mfma_f32_16x16x32_bf16(a[i], b1[j], acc1[i][j], 0, 0, 0);
        acc3[i][j] = __builtin_amdgcn_mfma_f32_16x16x32_bf16(a[i], b3[j], acc3[i][j], 0, 0, 0);
      }
    __syncthreads();
  }
#pragma unroll
  for (int i = 0; i < 4; i++) {
#pragma unroll
    for (int j = 0; j < 4; j++) {
#pragma unroll
      for (int r = 0; r < 4; r++) {
        int row = row0 + wm * 64 + i * 16 + quad * 4 + r;
        int col = bn + wn * 64 + j * 16 + ml;
        float v1 = acc1[i][j][r], v3 = acc3[i][j][r];
        float sil = v1 / (1.f + __expf(-v1));
        x13[(size_t)row * NI + col] = f2bf(sil * v3);
      }
    }
  }
}

// ---------------- MoE stage 2 split-K=2: pbuf[kh] = x13 @ w2^T (fp32 partials) ----------------
__global__ __launch_bounds__(256) void moe_stage2(
    const u16* __restrict__ x13, const u16* __restrict__ w2b,
    const int* __restrict__ tmap, float* __restrict__ pbuf) {
  __shared__ u16 As[128 * 32];
  __shared__ u16 Bs[128 * 32];
  if ((int)blockIdx.x >= tmap[0]) return;
  int entry = tmap[1 + blockIdx.x];
  int e = entry & 7;
  int row0 = (entry >> 3) * 128;
  int nt = blockIdx.y & 7, kh = blockIdx.y >> 3;
  int bn = nt * 128;
  int kbeg = kh * (NI / 2), kend = kbeg + NI / 2;
  const u16* Ag = x13 + (size_t)row0 * NI;
  const u16* Bg = w2b + (size_t)e * DD * NI + (size_t)bn * NI;
  float* Cp = pbuf + (size_t)kh * PCAP * DD;
  int tid = threadIdx.x, wave = tid >> 6, lane = tid & 63;
  int wm = wave >> 1, wn = wave & 1;
  int ml = lane & 15, quad = lane >> 4;

  floatx4 acc[4][4];
#pragma unroll
  for (int i = 0; i < 4; i++)
#pragma unroll
    for (int j = 0; j < 4; j++) acc[i][j] = (floatx4){0.f, 0.f, 0.f, 0.f};

  for (int k0 = kbeg; k0 < kend; k0 += 32) {
#pragma unroll
    for (int r = 0; r < 2; r++) {
      int s = tid + r * 256;
      int row = s >> 2, kc = (s & 3) * 8;
      __builtin_amdgcn_global_load_lds(
          (const __attribute__((address_space(1))) unsigned*)(Ag + (size_t)row * NI + k0 + kc),
          (__attribute__((address_space(3))) unsigned*)(As + s * 8), 16, 0, 0);
      __builtin_amdgcn_global_load_lds(
          (const __attribute__((address_space(1))) unsigned*)(Bg + (size_t)row * NI + k0 + kc),
          (__attribute__((address_space(3))) unsigned*)(Bs + s * 8), 16, 0, 0);
    }
    __syncthreads();
    short8 a[4], b[4];
#pragma unroll
    for (int i = 0; i < 4; i++)
      a[i] = *(const short8*)(As + ((wm * 64 + i * 16 + ml) * 32 + quad * 8));
#pragma unroll
    for (int j = 0; j < 4; j++)
      b[j] = *(const short8*)(Bs + ((wn * 64 + j * 16 + ml) * 32 + quad * 8));
#pragma unroll
    for (int i = 0; i < 4; i++)
#pragma unroll
      for (int j = 0; j < 4; j++)
        acc[i][j] = __builtin_amdgcn_mfma_f32_16x16x32_bf16(a[i], b[j], acc[i][j], 0, 0, 0);
    __syncthreads();
  }
#pragma unroll
  for (int i = 0; i < 4; i++) {
#pragma unroll
    for (int j = 0; j < 4; j++) {
#pragma unroll
      for (int r = 0; r < 4; r++) {
        int row = row0 + wm * 64 + i * 16 + quad * 4 + r;
        int col = bn + wn * 64 + j * 16 + ml;
        Cp[(size_t)row * DD + col] = acc[i][j][r];
      }
    }
  }
}

// ---------------- RoPE: fp32 qkv -> bf16 qT [NH][S][64] (scaled 1/8), kT [NKVH][S][64] ----------------
__global__ void rope_kernel(const float* __restrict__ qkv, const float* __restrict__ freqs,
                            u16* __restrict__ qT, u16* __restrict__ kT) {
  int s = blockIdx.x;
  int tid = threadIdx.x;
#pragma unroll
  for (int r = 0; r < 2; r++) {
    int tt = r * 256 + tid;
    int hh = tt >> 5, i = tt & 31;
    const float* p = qkv + (size_t)s * QKVN + hh * 64 + 2 * i;
    float c = freqs[(s * 32 + i) * 2], sn = freqs[(s * 32 + i) * 2 + 1];
    float x0 = p[0], x1 = p[1];
    float r0 = (x0 * c - x1 * sn) * 0.125f;
    float r1 = (x1 * c + x0 * sn) * 0.125f;
    unsigned pk = (unsigned)f2bf(r0) | ((unsigned)f2bf(r1) << 16);
    *(unsigned*)(qT + ((size_t)hh * SS + s) * 64 + 2 * i) = pk;
  }
  if (tid < 128) {
    int hh = tid >> 5, i = tid & 31;
    const float* p = qkv + (size_t)s * QKVN + DD + hh * 64 + 2 * i;
    float c = freqs[(s * 32 + i) * 2], sn = freqs[(s * 32 + i) * 2 + 1];
    float x0 = p[0], x1 = p[1];
    float r0 = x0 * c - x1 * sn;
    float r1 = x1 * c + x0 * sn;
    unsigned pk = (unsigned)f2bf(r0) | ((unsigned)f2bf(r1) << 16);
    *(unsigned*)(kT + ((size_t)hh * SS + s) * 64 + 2 * i) = pk;
  }
}

// ---------------- V transpose: qkv v-part -> vT2 [NKVH*64][S] bf16 ----------------
__global__ void vtrans_kernel(const float* __restrict__ qkv, u16* __restrict__ vT2) {
  __shared__ u16 tile[64][65];
  int bs = blockIdx.x * 64;
  int bc = blockIdx.y * 64;
  int tid = threadIdx.x;
#pragma unroll
  for (int it = 0; it < 4; it++) {
    int idx = it * 256 + tid;
    int r = idx >> 4, c4 = idx & 15;
    float4 v = *(const float4*)(qkv + (size_t)(bs + r) * QKVN + DD + 256 + bc + c4 * 4);
    tile[r][c4 * 4 + 0] = f2bf(v.x);
    tile[r][c4 * 4 + 1] = f2bf(v.y);
    tile[r][c4 * 4 + 2] = f2bf(v.z);
    tile[r][c4 * 4 + 3] = f2bf(v.w);
  }
  __syncthreads();
#pragma unroll
  for (int it = 0; it < 4; it++) {
    int idx = it * 256 + tid;
    int cc = idx >> 4, s4 = idx & 15;
    ushort4 o = make_ushort4(tile[s4 * 4 + 0][cc], tile[s4 * 4 + 1][cc],
                             tile[s4 * 4 + 2][cc], tile[s4 * 4 + 3][cc]);
    *(ushort4*)(vT2 + (size_t)(bc + cc) * SS + bs + s4 * 4) = o;
  }
}

// ---------------- Flash attention: BQ=128 (4 waves x 32 rows), BKV=64, MFMA ----------------
#define BQ 128
#define BKV 64
__global__ __launch_bounds__(256) void attn_flash(const u16* __restrict__ qT,
                                                  const u16* __restrict__ kT,
                                                  const u16* __restrict__ vT2,
                                                  u16* __restrict__ y) {
  __shared__ u16 Ks[2 * 64 * 32];
  __shared__ u16 Vs[2 * 64 * 32];
  __shared__ u16 Ps[2 * 128 * 36];
  int t = blockIdx.x;
  int h = blockIdx.y;
  int kvh = h >> 2;
  int bq = t * BQ;
  int tid = threadIdx.x, wave = tid >> 6, lane = tid & 63;
  int ml = lane & 15, quad = lane >> 4;

  short8 qf[2][2];
#pragma unroll
  for (int i = 0; i < 2; i++)
#pragma unroll
    for (int c = 0; c < 2; c++)
      qf[i][c] = *(const short8*)(qT + ((size_t)h * SS + bq + wave * 32 + i * 16 + ml) * 64 +
                                  c * 32 + quad * 8);

  float m_i[2][4], l_i[2][4];
  floatx4 o_acc[2][4];
#pragma unroll
  for (int i = 0; i < 2; i++)
#pragma unroll
    for (int r = 0; r < 4; r++) {
      m_i[i][r] = -1e30f;
      l_i[i][r] = 0.f;
      o_acc[i][r] = (floatx4){0.f, 0.f, 0.f, 0.f};
    }

  int nkv = 2 * t + 2;
  for (int kt = 0; kt < nkv; kt++) {
    int bk = kt * BKV;
    __syncthreads();
#pragma unroll
    for (int r = 0; r < 2; r++) {
      int ch = r * 256 + tid;
      int c = ch >> 8, srow = (ch >> 2) & 63, o8 = ch & 3;
      __builtin_amdgcn_global_load_lds(
          (const __attribute__((address_space(1))) unsigned*)(
              kT + ((size_t)kvh * SS + bk + srow) * 64 + c * 32 + o8 * 8),
          (__attribute__((address_space(3))) unsigned*)(Ks + ch * 8), 16, 0, 0);
      __builtin_amdgcn_global_load_lds(
          (const __attribute__((address_space(1))) unsigned*)(
              vT2 + ((size_t)kvh * 64 + srow) * SS + bk + c * 32 + o8 * 8),
          (__attribute__((address_space(3))) unsigned*)(Vs + ch * 8), 16, 0, 0);
    }
    __syncthreads();

    floatx4 s_acc[2][4];
#pragma unroll
    for (int i = 0; i < 2; i++)
#pragma unroll
      for (int j = 0; j < 4; j++) s_acc[i][j] = (floatx4){0.f, 0.f, 0.f, 0.f};
#pragma unroll
    for (int c = 0; c < 2; c++) {
#pragma unroll
      for (int jk = 0; jk < 4; jk++) {
        short8 kf = *(const short8*)(Ks + c * 2048 + (jk * 16 + ml) * 32 + quad * 8);
#pragma unroll
        for (int i = 0; i < 2; i++)
          s_acc[i][jk] = __builtin_amdgcn_mfma_f32_16x16x32_bf16(qf[i][c], kf, s_acc[i][jk], 0, 0, 0);
      }
    }
    if (bk + BKV - 1 > bq) {
#pragma unroll
      for (int i = 0; i < 2; i++)
#pragma unroll
        for (int jk = 0; jk < 4; jk++)
#pragma unroll
          for (int r = 0; r < 4; r++) {
            int row = bq + wave * 32 + i * 16 + quad * 4 + r;
            int col = bk + jk * 16 + ml;
            if (col > row) s_acc[i][jk][r] = -1e30f;
          }
    }
#pragma unroll
    for (int i = 0; i < 2; i++) {
#pragma unroll
      for (int r = 0; r < 4; r++) {
        float mx = -1e30f;
#pragma unroll
        for (int jk = 0; jk < 4; jk++) mx = fmaxf(mx, s_acc[i][jk][r]);
        for (int o = 1; o < 16; o <<= 1) mx = fmaxf(mx, __shfl_xor(mx, o));
        float mnew = fmaxf(m_i[i][r], mx);
        float alpha = __expf(m_i[i][r] - mnew);
        m_i[i][r] = mnew;
        float rs = 0.f;
#pragma unroll
        for (int jk = 0; jk < 4; jk++) {
          float p = __expf(s_acc[i][jk][r] - mnew);
          s_acc[i][jk][r] = p;
          rs += p;
        }
        for (int o = 1; o < 16; o <<= 1) rs += __shfl_xor(rs, o);
        l_i[i][r] = l_i[i][r] * alpha + rs;
#pragma unroll
        for (int jd = 0; jd < 4; jd++) o_acc[i][jd][r] *= alpha;
      }
    }
#pragma unroll
    for (int i = 0; i < 2; i++)
#pragma unroll
      for (int jk = 0; jk < 4; jk++)
#pragma unroll
        for (int r = 0; r < 4; r++) {
          int row = wave * 32 + i * 16 + quad * 4 + r;
          int col = jk * 16 + ml;
          Ps[(col >> 5) * (128 * 36) + row * 36 + (col & 31)] = f2bf(s_acc[i][jk][r]);
        }
#pragma unroll
    for (int kc = 0; kc < 2; kc++) {
      short8 pf[2];
#pragma unroll
      for (int i = 0; i < 2; i++)
        pf[i] = *(const short8*)(Ps + kc * (128 * 36) + (wave * 32 + i * 16 + ml) * 36 + quad * 8);
#pragma unroll
      for (int jd = 0; jd < 4; jd++) {
        short8 vf = *(const short8*)(Vs + kc * 2048 + (jd * 16 + ml) * 32 + quad * 8);
#pragma unroll
        for (int i = 0; i < 2; i++)
          o_acc[i][jd] = __builtin_amdgcn_mfma_f32_16x16x32_bf16(pf[i], vf, o_acc[i][jd], 0, 0, 0);
      }
    }
  }
#pragma unroll
  for (int i = 0; i < 2; i++) {
    float inv[4];
#pragma unroll
    for (int r = 0; r < 4; r++) inv[r] = 1.f / l_i[i][r];
#pragma unroll
    for (int jd = 0; jd < 4; jd++)
#pragma unroll
      for (int r = 0; r < 4; r++) {
        int row = bq + wave * 32 + i * 16 + quad * 4 + r;
        int col = h * 64 + jd * 16 + ml;
        y[(size_t)row * DD + col] = f2bf(o_acc[i][jd][r] * inv[r]);
      }
  }
}

// ---------------- Gate ----------------
__global__ __launch_bounds__(64) void gate_kernel(const float* __restrict__ hf,
                                                  const float* __restrict__ gw,
                                                  int* __restrict__ ei, float* __restrict__ ew,
                                                  int* __restrict__ cnt) {
  int t = blockIdx.x;
  int lane = threadIdx.x;
  const float* xr = hf + (size_t)t * DD;
  float acc[NE] = {};
  for (int c = 0; c < DD / 64; c++) {
    float xv = xr[lane + 64 * c];
#pragma unroll
    for (int e = 0; e < NE; e++) acc[e] += xv * gw[e * DD + lane + 64 * c];
  }
#pragma unroll
  for (int e = 0; e < NE; e++)
    for (int o = 32; o > 0; o >>= 1) acc[e] += __shfl_xor(acc[e], o);
  if (lane == 0) {
    float mx = acc[0];
    for (int e = 1; e < NE; e++) mx = fmaxf(mx, acc[e]);
    float p[NE], sum = 0.f;
    for (int e = 0; e < NE; e++) { p[e] = __expf(acc[e] - mx); sum += p[e]; }
    for (int e = 0; e < NE; e++) p[e] /= sum;
    int i0 = 0;
    for (int e = 1; e < NE; e++) if (p[e] > p[i0]) i0 = e;
    int i1 = (i0 == 0) ? 1 : 0;
    for (int e = 0; e < NE; e++) if (e != i0 && p[e] > p[i1]) i1 = e;
    float w0 = p[i0], w1 = p[i1], s = w0 + w1;
    ei[t * 2] = i0; ei[t * 2 + 1] = i1;
    ew[t * 2] = w0 / s; ew[t * 2 + 1] = w1 / s;
    atomicAdd(&cnt[i0], 1);
    atomicAdd(&cnt[i1], 1);
  }
}

__global__ void zero_cnt_kernel(int* cnt) {
  if (threadIdx.x < NE) cnt[threadIdx.x] = 0;
}

__global__ void prefix_kernel(const int* __restrict__ cnt, int* __restrict__ poff,
                              int* __restrict__ fill) {
  if (threadIdx.x == 0) {
    int pacc = 0;
    for (int e = 0; e < NE; e++) {
      poff[e] = pacc;
      pacc += (cnt[e] + 127) & ~127;
    }
    poff[NE] = pacc;
  }
  if (threadIdx.x < NE) fill[threadIdx.x] = 0;
}

// tmap[0] = ntiles, tmap[1+i] = (rowoff128 << 3) | expert
__global__ void tilemap_kernel(const int* __restrict__ poff, int* __restrict__ tmap) {
  if (threadIdx.x == 0) {
    int n = 0;
    for (int e = 0; e < NE; e++) {
      int r0 = poff[e] >> 7, r1 = poff[e + 1] >> 7;
      for (int r = r0; r < r1; r++) tmap[1 + n++] = (r << 3) | e;
    }
    tmap[0] = n;
  }
}

__global__ void fill_kernel(const int* __restrict__ ei, const int* __restrict__ poff,
                            int* __restrict__ fill, int* __restrict__ slot_of) {
  int t = blockIdx.x * blockDim.x + threadIdx.x;
  if (t >= SS) return;
  for (int a = 0; a < 2; a++) {
    int e = ei[t * 2 + a];
    int pos = atomicAdd(&fill[e], 1);
    slot_of[t * 2 + a] = poff[e] + pos;
  }
}

__global__ void gather_kernel(const u16* __restrict__ hf16, const int* __restrict__ slot_of,
                              u16* __restrict__ xslot) {
  int t = blockIdx.x;
  uint2 v = ((const uint2*)(hf16 + (size_t)t * DD))[threadIdx.x];
  for (int a = 0; a < 2; a++) {
    int slot = slot_of[t * 2 + a];
    ((uint2*)(xslot + (size_t)slot * DD))[threadIdx.x] = v;
  }
}

// out = h + w0*(p0[s0]+p1[s0]) + w1*(p0[s1]+p1[s1])
__global__ void final_kernel(const float* __restrict__ h, const float* __restrict__ p0,
                             const float* __restrict__ p1, const int* __restrict__ slot_of,
                             const float* __restrict__ ew, float* __restrict__ out) {
  int t = blockIdx.x;
  int s0 = slot_of[t * 2], s1 = slot_of[t * 2 + 1];
  float w0 = ew[t * 2], w1 = ew[t * 2 + 1];
  float4 hv = ((const float4*)(h + (size_t)t * DD))[threadIdx.x];
  float4 a0 = ((const float4*)(p0 + (size_t)s0 * DD))[threadIdx.x];
  float4 a1 = ((const float4*)(p1 + (size_t)s0 * DD))[threadIdx.x];
  float4 b0 = ((const float4*)(p0 + (size_t)s1 * DD))[threadIdx.x];
  float4 b1 = ((const float4*)(p1 + (size_t)s1 * DD))[threadIdx.x];
  float4 o;
  o.x = hv.x + w0 * (a0.x + a1.x) + w1 * (b0.x + b1.x);
  o.y = hv.y + w0 * (a0.y + a1.y) + w1 * (b0.y + b1.y);
  o.z = hv.z + w0 * (a0.z + a1.z) + w1 * (b0.z + b1.z);
  o.w = hv.w + w0 * (a0.w + a1.w) + w1 * (b0.w + b1.w);
  ((float4*)(out + (size_t)t * DD))[threadIdx.x] = o;
}

extern "C" void kernel_launch(void* const* d_in, const int* in_sizes, int n_in,
                              void* d_out, int out_size, void* d_ws, size_t ws_size,
                              hipStream_t stream) {
  const float* x = (const float*)d_in[0];
  const float* wqkv = (const float*)d_in[1];
  const float* wo = (const float*)d_in[2];
  const float* gate_w = (const float*)d_in[3];
  const float* w1 = (const float*)d_in[4];
  const float* w2 = (const float*)d_in[5];
  const float* w3 = (const float*)d_in[6];
  const float* attn_norm_w = (const float*)d_in[7];
  const float* ffn_norm_w = (const float*)d_in[8];
  const float* freqs = (const float*)d_in[9];
  float* out = (float*)d_out;

  char* ws = (char*)d_ws;
  size_t off = 0;
  auto alloc = [&](size_t bytes) -> char* {
    char* p = ws + off;
    off = (off + bytes + 255) & ~(size_t)255;
    return p;
  };
  u16* hn16    = (u16*)alloc((size_t)SS * DD * 2);   // aliased as qT after qkv GEMM
  float* qkv   = (float*)alloc((size_t)SS * QKVN * 4);
  u16* y16     = (u16*)alloc((size_t)SS * DD * 2);
  float* hbuf  = (float*)alloc((size_t)SS * DD * 4);
  float* hf    = (float*)alloc((size_t)SS * DD * 4);
  u16* hf16    = (u16*)alloc((size_t)SS * DD * 2);
  u16* kT      = (u16*)alloc((size_t)NKVH * SS * HDIM * 2);
  u16* vT2     = (u16*)alloc((size_t)NKVH * HDIM * SS * 2);
  u16* wqkv16  = (u16*)alloc((size_t)QKVN * DD * 2);
  u16* wo16    = (u16*)alloc((size_t)DD * DD * 2);
  u16* w1_16   = (u16*)alloc((size_t)NE * NI * DD * 2);
  u16* w3_16   = (u16*)alloc((size_t)NE * NI * DD * 2);
  u16* w2_16   = (u16*)alloc((size_t)NE * DD * NI * 2);
  u16* xslot   = (u16*)alloc((size_t)PCAP * DD * 2);
  u16* x13     = (u16*)alloc((size_t)PCAP * NI * 2);
  float* pbuf  = (float*)alloc((size_t)2 * PCAP * DD * 4);
  int* ei      = (int*)alloc((size_t)SS * 2 * 4);
  float* ew    = (float*)alloc((size_t)SS * 2 * 4);
  int* slot_of = (int*)alloc((size_t)SS * 2 * 4);
  int* cnt     = (int*)alloc(NE * 4);
  int* poff    = (int*)alloc((NE + 1) * 4);
  int* fill    = (int*)alloc(NE * 4);
  int* tmap    = (int*)alloc((NTILEMAX + 1) * 4);
  u16* qT      = hn16;

  auto conv = [&](const float* src, u16* dst, size_t n) {
    int n4 = (int)(n / 4);
    f32_to_bf16_kernel<<<(n4 + 255) / 256, 256, 0, stream>>>(src, dst, n4);
  };

  zero_cnt_kernel<<<1, 64, 0, stream>>>(cnt);
  conv(wqkv, wqkv16, (size_t)QKVN * DD);
  conv(wo, wo16, (size_t)DD * DD);
  conv(w1, w1_16, (size_t)NE * NI * DD);
  conv(w3, w3_16, (size_t)NE * NI * DD);
  conv(w2, w2_16, (size_t)NE * DD * NI);

  // ---- attention path ----
  rmsnorm_kernel<<<SS, 256, 0, stream>>>(x, attn_norm_w, nullptr, hn16);
  gemm128<<<dim3(SS / 128, QKVN / 128), 256, 0, stream>>>(hn16, wqkv16, qkv, nullptr, QKVN, DD);
  rope_kernel<<<SS, 256, 0, stream>>>(qkv, freqs, qT, kT);
  vtrans_kernel<<<dim3(SS / 64, 4), 256, 0, stream>>>(qkv, vT2);
  attn_flash<<<dim3(SS / BQ, NH), 256, 0, stream>>>(qT, kT, vT2, y16);
  gemm128<<<dim3(SS / 128, DD / 128), 256, 0, stream>>>(y16, wo16, hbuf, x, DD, DD);

  // ---- MoE path ----
  rmsnorm_kernel<<<SS, 256, 0, stream>>>(hbuf, ffn_norm_w, hf, hf16);
  gate_kernel<<<SS, 64, 0, stream>>>(hf, gate_w, ei, ew, cnt);
  prefix_kernel<<<1, 64, 0, stream>>>(cnt, poff, fill);
  tilemap_kernel<<<1, 64, 0, stream>>>(poff, tmap);
  fill_kernel<<<(SS + 255) / 256, 256, 0, stream>>>(ei, poff, fill, slot_of);
  gather_kernel<<<SS, 256, 0, stream>>>(hf16, slot_of, xslot);
  moe_stage1<<<dim3(NTILEMAX, NI / 128), 256, 0, stream>>>(xslot, w1_16, w3_16, tmap, x13);
  moe_stage2<<<dim3(NTILEMAX, 16), 256, 0, stream>>>(x13, w2_16, tmap, pbuf);
  final_kernel<<<SS, 256, 0, stream>>>(hbuf, pbuf, pbuf + (size_t)PCAP * DD, slot_of, ew, out);
}